// Round 6
// baseline (126.102 us; speedup 1.0000x reference)
//
#include <hip/hip_runtime.h>
#include <hip/hip_bf16.h>
#include <stdint.h>

typedef unsigned short u16;
typedef __attribute__((ext_vector_type(8))) short bf16x8;   // 8 bf16 = 4 VGPR (MFMA A/B frag)
typedef __attribute__((ext_vector_type(4))) float f32x4;
typedef __attribute__((ext_vector_type(16))) float f32x16;

// ---------- helpers ----------
__device__ __forceinline__ u16 f2bf(float f) {          // RNE f32 -> bf16 (finite inputs)
  union { float f; uint32_t u; } a; a.f = f;
  return (u16)((a.u + 0x7FFFu + ((a.u >> 16) & 1u)) >> 16);
}

__device__ __forceinline__ void gload_lds16(const void* g, void* l) {
  // direct global->LDS, 16B per lane; LDS dest = wave-uniform base + lane*16
  auto* gp = (__attribute__((address_space(1))) void*)(uintptr_t)g;
  auto* lp = (__attribute__((address_space(3))) void*)(uintptr_t)l;
  __builtin_amdgcn_global_load_lds(gp, lp, 16, 0, 0);
}

__device__ __forceinline__ float exp2_fast(float x) {
  float r;
  asm("v_exp_f32 %0, %1" : "=v"(r) : "v"(x));
  return r;
}

template <int N> __device__ __forceinline__ void waitvm() {
  if constexpr (N == 3)      asm volatile("s_waitcnt vmcnt(3)" ::: "memory");
  else if constexpr (N == 4) asm volatile("s_waitcnt vmcnt(4)" ::: "memory");
  else                       asm volatile("s_waitcnt vmcnt(0)" ::: "memory");
}

#define CVTPK(d, a, b) asm("v_cvt_pk_bf16_f32 %0, %1, %2" : "=v"(d) : "v"(a), "v"(b))
#define SWAP32(a, b)   asm("v_permlane32_swap_b32 %0, %1" : "+v"(a), "+v"(b))
#define BARRIER() do { asm volatile("" ::: "memory"); __builtin_amdgcn_s_barrier(); asm volatile("" ::: "memory"); } while (0)

// ---------- 0: f32 -> bf16 conversion / concat ----------
__global__ void cvt_kernel(const float4* __restrict__ x, const float4* __restrict__ wq,
                           const float4* __restrict__ wk, const float4* __restrict__ wv,
                           const float4* __restrict__ wo,
                           ushort4* __restrict__ xb, ushort4* __restrict__ wqkv,
                           ushort4* __restrict__ wob) {
  const int XN = (2 * 2048 * 1024) / 4;   // 1048576
  const int WN = (1024 * 1024) / 4;       // 262144  (2^18)
  const int total = XN + 4 * WN;
  for (int i = blockIdx.x * 256 + threadIdx.x; i < total; i += gridDim.x * 256) {
    float4 v; ushort4* dst;
    if (i < XN) { v = x[i]; dst = xb + i; }
    else {
      int j = i - XN; int m = j >> 18; int o = j & (WN - 1);
      const float4* src = (m == 0) ? wq : (m == 1) ? wk : (m == 2) ? wv : wo;
      v = src[o];
      dst = (m < 3) ? (wqkv + j) : (wob + o);
    }
    ushort4 r; r.x = f2bf(v.x); r.y = f2bf(v.y); r.z = f2bf(v.z); r.w = f2bf(v.w);
    *dst = r;
  }
}

// ---------- 1: lengths from prefix padding mask ----------
__global__ void len_kernel(const int* __restrict__ mask, int* __restrict__ lens) {
  __shared__ int red[256];
  int b = blockIdx.x, s = 0;
  for (int i = threadIdx.x; i < 2048; i += 256) s += mask[b * 2048 + i];
  red[threadIdx.x] = s;
  __syncthreads();
  if (threadIdx.x < 64) {
    int v = red[threadIdx.x] + red[threadIdx.x + 64] + red[threadIdx.x + 128] + red[threadIdx.x + 192];
    #pragma unroll
    for (int o = 32; o > 0; o >>= 1) v += __shfl_down(v, o);
    if (threadIdx.x == 0) lens[b] = v;
  }
}

// ---------- 2/4: triple-buffered counted-vmcnt BT GEMM, 32x32x16 MFMA ----------
// out[m][n] = sum_k A[m][k]*B[n][k], K=1024, BK=32, 4 waves (2x2 of 64x(BN/2)).
// MODE 0: f32 store to outf (N=1024). MODE 1: RoPE+scatter (N=3072), V natural.
template <int BM, int BN, int MODE>
__global__ __launch_bounds__(256, 3)
void gemm32(const u16* __restrict__ A, const u16* __restrict__ Bm,
            int nTm, float* __restrict__ outf,
            u16* __restrict__ Qb, u16* __restrict__ Kb, u16* __restrict__ Vb,
            const float* __restrict__ cosT, const float* __restrict__ sinT) {
  constexpr int MF = BM / 64;         // 32-row frags per wave (wave m-span = BM/2)
  constexpr int NF = BN / 64;
  constexpr int LA = BM / 64;         // gload_lds16 per thread per A tile
  constexpr int LB = BN / 64;
  constexpr int LOADS = LA + LB;
  __shared__ alignas(16) u16 SA[3][BM * 32];
  __shared__ alignas(16) u16 SB[3][BN * 32];

  const int tid = threadIdx.x, lane = tid & 63, wid = tid >> 6;
  const int wm = (wid >> 1) * (BM / 2), wn = (wid & 1) * (BN / 2);
  const int l31 = lane & 31, hi = lane >> 5;

  // XCD-aware swizzle (gridDim.x % 8 == 0)
  const int cpx = gridDim.x >> 3;
  const int bid = (blockIdx.x & 7) * cpx + (blockIdx.x >> 3);
  const int m0 = (bid % nTm) * BM;
  const int n0 = (bid / nTm) * BN;

  // staging: thread t covers row (t>>2); storage slot s holds global chunk
  // s ^ f(row), f(row) = (row>>1)&3  -> frag reads conflict-free (verified 0)
  const int srow = tid >> 2;
  const int schunk = (tid & 3) ^ ((srow >> 1) & 3);
  const u16* gA = A + (int64_t)(m0 + srow) * 1024 + schunk * 8;
  const u16* gB = Bm + (int64_t)(n0 + srow) * 1024 + schunk * 8;
  const int sdst = wid * 512;   // u16 offset; +j*2048; HW adds lane*16B

#define STAGE(b, t) do { const int _ko = (t) * 32; \
    _Pragma("unroll") for (int j = 0; j < LA; ++j) \
      gload_lds16(gA + (int64_t)(j * 64) * 1024 + _ko, &SA[b][j * 2048 + sdst]); \
    _Pragma("unroll") for (int j = 0; j < LB; ++j) \
      gload_lds16(gB + (int64_t)(j * 64) * 1024 + _ko, &SB[b][j * 2048 + sdst]); } while (0)

  f32x16 acc[MF][NF];
  #pragma unroll
  for (int i = 0; i < MF; ++i)
    #pragma unroll
    for (int j = 0; j < NF; ++j)
      #pragma unroll
      for (int e = 0; e < 16; ++e) acc[i][j][e] = 0.0f;

  STAGE(0, 0);
  STAGE(1, 1);
  waitvm<LOADS>();    // tile0 landed (tile1 may still be in flight)
  BARRIER();

  int bc = 0, bs = 2;   // compute buffer, stage-target buffer
  for (int t = 0; t < 32; ++t) {
    if (t < 30) STAGE(bs, t + 2);
    const u16* sa = SA[bc];
    const u16* sb = SB[bc];
    // frags: lane holds M[row = base + l31][k = kh*16 + hi*8 + j] (16B contiguous)
    bf16x8 af[MF][2], bfm[NF][2];
    #pragma unroll
    for (int mf = 0; mf < MF; ++mf)
      #pragma unroll
      for (int kh = 0; kh < 2; ++kh) {
        const int row = wm + mf * 32 + l31;
        af[mf][kh] = *(const bf16x8*)&sa[row * 32 + (((kh * 2 + hi) ^ ((row >> 1) & 3)) * 8)];
      }
    #pragma unroll
    for (int nf = 0; nf < NF; ++nf)
      #pragma unroll
      for (int kh = 0; kh < 2; ++kh) {
        const int row = wn + nf * 32 + l31;
        bfm[nf][kh] = *(const bf16x8*)&sb[row * 32 + (((kh * 2 + hi) ^ ((row >> 1) & 3)) * 8)];
      }
    #pragma unroll
    for (int kh = 0; kh < 2; ++kh)
      #pragma unroll
      for (int mf = 0; mf < MF; ++mf)
        #pragma unroll
        for (int nf = 0; nf < NF; ++nf)
          acc[mf][nf] = __builtin_amdgcn_mfma_f32_32x32x16_bf16(af[mf][kh], bfm[nf][kh], acc[mf][nf], 0, 0, 0);
    if (t < 30) waitvm<LOADS>();   // tile t+1 landed; just-issued t+2 stays in flight
    else        waitvm<0>();
    BARRIER();
    bc = (bc == 2) ? 0 : bc + 1;
    bs = (bs == 2) ? 0 : bs + 1;
  }

  // C/D 32x32: col = l31, row = (reg&3) + 8*(reg>>2) + 4*hi
  if (MODE == 0) {
    #pragma unroll
    for (int mf = 0; mf < MF; ++mf)
      #pragma unroll
      for (int reg = 0; reg < 16; ++reg) {
        const int row = m0 + wm + mf * 32 + (reg & 3) + 8 * (reg >> 2) + 4 * hi;
        float* orow = outf + (int64_t)row * 1024 + n0 + wn + l31;
        #pragma unroll
        for (int nf = 0; nf < NF; ++nf) orow[nf * 32] = acc[mf][nf][reg];
      }
  } else {
    #pragma unroll
    for (int mf = 0; mf < MF; ++mf) {
      #pragma unroll
      for (int reg = 0; reg < 16; ++reg) {
        const int row = m0 + wm + mf * 32 + (reg & 3) + 8 * (reg >> 2) + 4 * hi;
        const int bb = row >> 11, ss = row & 2047;
        #pragma unroll
        for (int nf = 0; nf < NF; ++nf) {
          const int n = n0 + wn + nf * 32 + l31;
          float v = acc[mf][nf][reg];
          const int h = (n >> 6) & 15, d = n & 63;
          const int idx = ((bb * 16 + h) * 2048 + ss) * 64 + d;
          if (n < 2048) {                       // Q or K: RoPE (block-uniform branch)
            float partner = __shfl_xor(v, 1);
            const int ii = (n >> 1) & 31;
            const float c = cosT[ss * 32 + ii];
            const float sn = sinT[ss * 32 + ii];
            float rv = (n & 1) ? (partner * sn + v * c) : (v * c - partner * sn);
            // Q: fold 1/sqrt(D)=1/32 AND log2(e) so softmax runs in exp2 domain
            if (n < 1024) Qb[idx] = f2bf(rv * 0.0450842298f);
            else          Kb[idx] = f2bf(rv);
          } else {                              // V: natural [bh][s][64] (cheap store)
            Vb[idx] = f2bf(v);
          }
        }
      }
    }
  }
#undef STAGE
}

// ---------- 2.5: V [bh][s][64] -> V^T [bh][d][2048], zero-LDS 8x8 reg transpose ----------
__global__ __launch_bounds__(256)
void vtrans(const u16* __restrict__ VB, u16* __restrict__ VbT) {
  const int bh = blockIdx.x >> 3, s0 = (blockIdx.x & 7) * 256;
  const int t = threadIdx.x;
  const int d8 = (t & 7) * 8;             // d-block
  const int s8 = s0 + (t >> 3) * 8;       // s-block
  const u16* src = VB + ((int64_t)bh * 2048 + s8) * 64 + d8;
  uint32_t r[8][4];
  #pragma unroll
  for (int j = 0; j < 8; ++j) *(uint4*)&r[j][0] = *(const uint4*)(src + j * 64);
  // 8x8 u16 transpose: w[d][rp] = (r[2rp][d-pair] , r[2rp+1][d-pair]) via v_perm
  uint32_t w[8][4];
  #pragma unroll
  for (int rp = 0; rp < 4; ++rp)
    #pragma unroll
    for (int k = 0; k < 4; ++k) {
      w[2 * k][rp]     = __builtin_amdgcn_perm(r[2 * rp + 1][k], r[2 * rp][k], 0x05040100u);
      w[2 * k + 1][rp] = __builtin_amdgcn_perm(r[2 * rp + 1][k], r[2 * rp][k], 0x07060302u);
    }
  u16* dst = VbT + ((int64_t)bh * 64 + d8) * 2048 + s8;
  #pragma unroll
  for (int i = 0; i < 8; ++i) *(uint4*)(dst + (int64_t)i * 2048) = *(uint4*)&w[i][0];
}

// ---------- 3: flash attention ----------
// grid: 512 = 32 (b*h) * 16 qblocks; block: 4 waves, each owns 32 q-rows.
// KVBLK=64. swapped QK^T: S^T = mfma32x32x16(K, Q) -> lane owns query ql,
// 32 of 64 key-scores in-lane (hi split with lane^32 partner).
// P fragments built fully in-register via v_cvt_pk_bf16_f32 + v_permlane32_swap.
__global__ __launch_bounds__(256, 2)
void attn_kernel(const u16* __restrict__ Qb, const u16* __restrict__ Kb,
                 const u16* __restrict__ VbT, u16* __restrict__ attnb,
                 const int* __restrict__ lens) {
  __shared__ alignas(16) u16 Klds[2][64 * 64];   // [key][d], 128B rows, slot^=(row&7)
  __shared__ alignas(16) u16 Vlds[2][64 * 64];   // [d][key], 128B rows, slot^=(row&7)
  const int tid = threadIdx.x, lane = tid & 63, wid = tid >> 6;
  const int hi = lane >> 5, ql = lane & 31;
  const int bh = blockIdx.x >> 4;
  const int len = lens[bh >> 4];
  const int qrow = (blockIdx.x & 15) * 128 + wid * 32 + ql;

  // Q fragments (loop-invariant): B-operand, chunk c: d = c*16 + hi*8 + j
  bf16x8 qf[4];
  const u16* qptr = Qb + ((int64_t)bh * 2048 + qrow) * 64 + hi * 8;
  #pragma unroll
  for (int c = 0; c < 4; ++c) qf[c] = *(const bf16x8*)(qptr + c * 16);

  // staging: pre-swizzled global source, linear LDS dest (G21)
  const int srow = tid >> 3, schunk = (tid & 7) ^ (srow & 7);
  const u16* kg = Kb + ((int64_t)bh * 2048 + srow) * 64 + schunk * 8;
  const u16* vg = VbT + ((int64_t)bh * 64 + srow) * 2048 + schunk * 8;
  const int dstoff = wid * 512;                  // u16; HW adds lane*16B

  f32x16 oacc[2];
  #pragma unroll
  for (int r = 0; r < 16; ++r) { oacc[0][r] = 0.0f; oacc[1][r] = 0.0f; }
  float mrun = -1e30f, lrun = 0.0f;

  const int nt = (len + 63) >> 6;
  gload_lds16(kg,             &Klds[0][dstoff]);
  gload_lds16(kg + 32 * 64,   &Klds[0][2048 + dstoff]);
  gload_lds16(vg,             &Vlds[0][dstoff]);
  gload_lds16(vg + 32 * 2048, &Vlds[0][2048 + dstoff]);
  __syncthreads();

  const u16* kgn = kg + 64 * 64;   // next-tile pointers
  const u16* vgn = vg + 64;

  for (int t = 0; t < nt; ++t) {
    const int bu = t & 1;
    if (t + 1 < nt) {                       // prefetch next tile into other buffer
      gload_lds16(kgn,             &Klds[bu ^ 1][dstoff]);
      gload_lds16(kgn + 32 * 64,   &Klds[bu ^ 1][2048 + dstoff]);
      gload_lds16(vgn,             &Vlds[bu ^ 1][dstoff]);
      gload_lds16(vgn + 32 * 2048, &Vlds[bu ^ 1][2048 + dstoff]);
    }
    kgn += 64 * 64; vgn += 64;

    // QK^T: A = K rows (key = kh*32 + ql), B = Q frags
    f32x16 s0, s1;
    #pragma unroll
    for (int r = 0; r < 16; ++r) { s0[r] = 0.0f; s1[r] = 0.0f; }
    __builtin_amdgcn_s_setprio(1);
    #pragma unroll
    for (int c = 0; c < 4; ++c) {
      const int slot = (((2 * c + hi) ^ (ql & 7)) * 8);
      bf16x8 kf0 = *(const bf16x8*)&Klds[bu][ql * 64 + slot];
      bf16x8 kf1 = *(const bf16x8*)&Klds[bu][(32 + ql) * 64 + slot];
      s0 = __builtin_amdgcn_mfma_f32_32x32x16_bf16(kf0, qf[c], s0, 0, 0, 0);
      s1 = __builtin_amdgcn_mfma_f32_32x32x16_bf16(kf1, qf[c], s1, 0, 0, 0);
    }
    __builtin_amdgcn_s_setprio(0);

    const int k0 = t * 64;
    if (k0 + 64 > len) {                    // mask padded keys (last tile only)
      #pragma unroll
      for (int r = 0; r < 16; ++r) {
        const int key = k0 + (r & 3) + 8 * (r >> 2) + 4 * hi;
        if (key >= len) s0[r] = -1e30f;
        if (key + 32 >= len) s1[r] = -1e30f;
      }
    }

    // online softmax (exp2 domain; log2e folded into Q)
    float ma = fmaxf(s0[0], s1[0]), mb = fmaxf(s0[1], s1[1]);
    float mc = fmaxf(s0[2], s1[2]), md = fmaxf(s0[3], s1[3]);
    #pragma unroll
    for (int r = 4; r < 16; r += 4) {
      ma = fmaxf(ma, fmaxf(s0[r], s1[r]));
      mb = fmaxf(mb, fmaxf(s0[r + 1], s1[r + 1]));
      mc = fmaxf(mc, fmaxf(s0[r + 2], s1[r + 2]));
      md = fmaxf(md, fmaxf(s0[r + 3], s1[r + 3]));
    }
    float mx = fmaxf(fmaxf(ma, mb), fmaxf(mc, md));
    mx = fmaxf(mx, __shfl_xor(mx, 32));
    if (!__all(mx - mrun <= 11.0f)) {       // defer-max (T13): rescale only on real growth
      const float mnew = fmaxf(mrun, mx);
      const float sc = exp2_fast(mrun - mnew);
      #pragma unroll
      for (int r = 0; r < 16; ++r) { oacc[0][r] *= sc; oacc[1][r] *= sc; }
      lrun *= sc;
      mrun = mnew;
    }
    float p[32];
    float ps0 = 0.0f, ps1 = 0.0f, ps2 = 0.0f, ps3 = 0.0f;
    #pragma unroll
    for (int r = 0; r < 16; r += 4) {
      p[r]      = exp2_fast(s0[r] - mrun);
      p[r + 1]  = exp2_fast(s0[r + 1] - mrun);
      p[r + 2]  = exp2_fast(s0[r + 2] - mrun);
      p[r + 3]  = exp2_fast(s0[r + 3] - mrun);
      p[16 + r]     = exp2_fast(s1[r] - mrun);
      p[16 + r + 1] = exp2_fast(s1[r + 1] - mrun);
      p[16 + r + 2] = exp2_fast(s1[r + 2] - mrun);
      p[16 + r + 3] = exp2_fast(s1[r + 3] - mrun);
      ps0 += p[r] + p[16 + r];
      ps1 += p[r + 1] + p[16 + r + 1];
      ps2 += p[r + 2] + p[16 + r + 2];
      ps3 += p[r + 3] + p[16 + r + 3];
    }
    float psum = (ps0 + ps1) + (ps2 + ps3);
    psum += __shfl_xor(psum, 32);
    lrun += psum;

    // P -> bf16 MFMA B-fragments fully in-register (T12)
    bf16x8 pfrag[4];
    #pragma unroll
    for (int ks = 0; ks < 4; ++ks) {
      uint32_t a0, a1, a2, a3;
      CVTPK(a0, p[8 * ks + 0], p[8 * ks + 1]);
      CVTPK(a1, p[8 * ks + 2], p[8 * ks + 3]);
      CVTPK(a2, p[8 * ks + 4], p[8 * ks + 5]);
      CVTPK(a3, p[8 * ks + 6], p[8 * ks + 7]);
      SWAP32(a0, a2);
      SWAP32(a1, a3);
      union { uint32_t u[4]; bf16x8 v; } pw;
      pw.u[0] = a0; pw.u[1] = a1; pw.u[2] = a2; pw.u[3] = a3;
      pfrag[ks] = pw.v;
    }

    // PV: O^T += V^T * P   (A = V^T rows d = dc*32 + ql)
    __builtin_amdgcn_s_setprio(1);
    #pragma unroll
    for (int dc = 0; dc < 2; ++dc) {
      const int drow = dc * 32 + ql;
      #pragma unroll
      for (int ks = 0; ks < 4; ++ks) {
        const int slot = (((2 * ks + hi) ^ (ql & 7)) * 8);
        bf16x8 vf = *(const bf16x8*)&Vlds[bu][drow * 64 + slot];
        oacc[dc] = __builtin_amdgcn_mfma_f32_32x32x16_bf16(vf, pfrag[ks], oacc[dc], 0, 0, 0);
      }
    }
    __builtin_amdgcn_s_setprio(0);
    __syncthreads();
  }

  // epilogue: normalize, write attn[row][h*64+d] as bf16
  const float inv = 1.0f / lrun;
  u16* outp = attnb + ((int64_t)((bh >> 4) * 2048 + qrow)) * 1024 + (bh & 15) * 64;
  #pragma unroll
  for (int dc = 0; dc < 2; ++dc)
    #pragma unroll
    for (int g = 0; g < 4; ++g) {
      ushort4 w;
      w.x = f2bf(oacc[dc][4 * g + 0] * inv);
      w.y = f2bf(oacc[dc][4 * g + 1] * inv);
      w.z = f2bf(oacc[dc][4 * g + 2] * inv);
      w.w = f2bf(oacc[dc][4 * g + 3] * inv);
      *(ushort4*)(outp + dc * 32 + 8 * g + 4 * hi) = w;
    }
}

// ---------- launch ----------
extern "C" void kernel_launch(void* const* d_in, const int* in_sizes, int n_in,
                              void* d_out, int out_size, void* d_ws, size_t ws_size,
                              hipStream_t stream) {
  const float* x    = (const float*)d_in[0];
  const float* wq   = (const float*)d_in[1];
  const float* wk   = (const float*)d_in[2];
  const float* wv   = (const float*)d_in[3];
  const float* wo   = (const float*)d_in[4];
  const float* fcos = (const float*)d_in[5];
  const float* fsin = (const float*)d_in[6];
  const int*   pmsk = (const int*)d_in[7];
  float* out = (float*)d_out;

  char* ws = (char*)d_ws;
  u16* XB    = (u16*)(ws);                          // 8 MB
  u16* WQKV  = (u16*)(ws + (size_t)8  * 1048576);   // 6 MB
  u16* WOB   = (u16*)(ws + (size_t)14 * 1048576);   // 2 MB
  u16* QB    = (u16*)(ws + (size_t)16 * 1048576);   // 8 MB
  u16* KB    = (u16*)(ws + (size_t)24 * 1048576);   // 8 MB
  u16* VBT   = (u16*)(ws + (size_t)32 * 1048576);   // 8 MB
  u16* ATTNB = (u16*)(ws + (size_t)40 * 1048576);   // 8 MB (also V-natural before attn)
  int* LENS  = (int*)(ws + (size_t)48 * 1048576);
  u16* VB    = ATTNB;   // V natural lives here until vtrans consumes it

  cvt_kernel<<<2048, 256, 0, stream>>>((const float4*)x, (const float4*)wq,
                                       (const float4*)wk, (const float4*)wv,
                                       (const float4*)wo, (ushort4*)XB,
                                       (ushort4*)WQKV, (ushort4*)WOB);
  len_kernel<<<2, 256, 0, stream>>>(pmsk, LENS);

  // QKV projection: M=4096 (32 m-tiles), N=3072 (24 n-tiles) -> 768 blocks
  gemm32<128, 128, 1><<<768, 256, 0, stream>>>(XB, WQKV, 32, nullptr,
                                               QB, KB, VB, fcos, fsin);

  // V natural -> V^T
  vtrans<<<256, 256, 0, stream>>>(VB, VBT);

  attn_kernel<<<512, 256, 0, stream>>>(QB, KB, VBT, ATTNB, LENS);

  // out-proj: M=4096 (32 m-tiles), N=1024 (16 n-tiles of 64) -> 512 blocks
  gemm32<128, 64, 0><<<512, 256, 0, stream>>>(ATTNB, WOB, 32, out,
                                              nullptr, nullptr, nullptr, nullptr, nullptr);
}

// Round 7
// 120.235 us; speedup vs baseline: 1.0488x; 1.0488x over previous
//
#include <hip/hip_runtime.h>
#include <hip/hip_bf16.h>
#include <stdint.h>

typedef unsigned short u16;
typedef __attribute__((ext_vector_type(8))) short bf16x8;   // 8 bf16 = 4 VGPR (MFMA A/B frag)
typedef __attribute__((ext_vector_type(4))) float f32x4;
typedef __attribute__((ext_vector_type(16))) float f32x16;

// ---------- helpers ----------
__device__ __forceinline__ u16 f2bf(float f) {          // RNE f32 -> bf16 (finite inputs)
  union { float f; uint32_t u; } a; a.f = f;
  return (u16)((a.u + 0x7FFFu + ((a.u >> 16) & 1u)) >> 16);
}

__device__ __forceinline__ void gload_lds16(const void* g, void* l) {
  // direct global->LDS, 16B per lane; LDS dest = wave-uniform base + lane*16
  auto* gp = (__attribute__((address_space(1))) void*)(uintptr_t)g;
  auto* lp = (__attribute__((address_space(3))) void*)(uintptr_t)l;
  __builtin_amdgcn_global_load_lds(gp, lp, 16, 0, 0);
}

__device__ __forceinline__ float exp2_fast(float x) {
  float r;
  asm("v_exp_f32 %0, %1" : "=v"(r) : "v"(x));
  return r;
}

template <int N> __device__ __forceinline__ void waitvm() {
  if constexpr (N == 3)      asm volatile("s_waitcnt vmcnt(3)" ::: "memory");
  else if constexpr (N == 4) asm volatile("s_waitcnt vmcnt(4)" ::: "memory");
  else                       asm volatile("s_waitcnt vmcnt(0)" ::: "memory");
}

#define CVTPK(d, a, b) asm("v_cvt_pk_bf16_f32 %0, %1, %2" : "=v"(d) : "v"(a), "v"(b))
#define SWAP32(a, b)   asm("v_permlane32_swap_b32 %0, %1" : "+v"(a), "+v"(b))
#define BARRIER() do { asm volatile("" ::: "memory"); __builtin_amdgcn_s_barrier(); asm volatile("" ::: "memory"); } while (0)

// ---------- 0: f32 -> bf16 conversion / concat ----------
__global__ void cvt_kernel(const float4* __restrict__ x, const float4* __restrict__ wq,
                           const float4* __restrict__ wk, const float4* __restrict__ wv,
                           const float4* __restrict__ wo,
                           ushort4* __restrict__ xb, ushort4* __restrict__ wqkv,
                           ushort4* __restrict__ wob) {
  const int XN = (2 * 2048 * 1024) / 4;   // 1048576
  const int WN = (1024 * 1024) / 4;       // 262144  (2^18)
  const int total = XN + 4 * WN;
  for (int i = blockIdx.x * 256 + threadIdx.x; i < total; i += gridDim.x * 256) {
    float4 v; ushort4* dst;
    if (i < XN) { v = x[i]; dst = xb + i; }
    else {
      int j = i - XN; int m = j >> 18; int o = j & (WN - 1);
      const float4* src = (m == 0) ? wq : (m == 1) ? wk : (m == 2) ? wv : wo;
      v = src[o];
      dst = (m < 3) ? (wqkv + j) : (wob + o);
    }
    ushort4 r; r.x = f2bf(v.x); r.y = f2bf(v.y); r.z = f2bf(v.z); r.w = f2bf(v.w);
    *dst = r;
  }
}

// ---------- 1: lengths from prefix padding mask ----------
__global__ void len_kernel(const int* __restrict__ mask, int* __restrict__ lens) {
  __shared__ int red[256];
  int b = blockIdx.x, s = 0;
  for (int i = threadIdx.x; i < 2048; i += 256) s += mask[b * 2048 + i];
  red[threadIdx.x] = s;
  __syncthreads();
  if (threadIdx.x < 64) {
    int v = red[threadIdx.x] + red[threadIdx.x + 64] + red[threadIdx.x + 128] + red[threadIdx.x + 192];
    #pragma unroll
    for (int o = 32; o > 0; o >>= 1) v += __shfl_down(v, o);
    if (threadIdx.x == 0) lens[b] = v;
  }
}

// ---------- 2/4: triple-buffered counted-vmcnt BT GEMM (R5 structure, 0 conflicts) ----------
// out[m][n] = sum_k A[m][k]*B[n][k], K=1024, BK=32, 4 waves (2x2).
// MODE 0: f32 store to outf (N=1024). MODE 1: RoPE+scatter (N=3072).
template <int BM, int BN, int MODE>
__global__ __launch_bounds__(256, 3)
void gemm3(const u16* __restrict__ A, const u16* __restrict__ Bm,
           int nTm, float* __restrict__ outf,
           u16* __restrict__ Qb, u16* __restrict__ Kb, u16* __restrict__ VbT,
           const float* __restrict__ cosT, const float* __restrict__ sinT) {
  constexpr int MREP = BM / 32;       // 16-row frags per wave (wave spans BM/2)
  constexpr int NREP = BN / 32;
  constexpr int LA = BM / 64;         // gload_lds16 per thread per A tile
  constexpr int LB = BN / 64;
  constexpr int LOADS = LA + LB;
  __shared__ alignas(16) u16 SA[3][BM * 32];
  __shared__ alignas(16) u16 SB[3][BN * 32];

  const int tid = threadIdx.x, lane = tid & 63, wid = tid >> 6;
  const int wm = (wid >> 1) * (BM / 2), wn = (wid & 1) * (BN / 2);
  const int lr = lane & 15, lg = lane >> 4;

  // XCD-aware swizzle (gridDim.x % 8 == 0)
  const int cpx = gridDim.x >> 3;
  const int bid = (blockIdx.x & 7) * cpx + (blockIdx.x >> 3);
  const int m0 = (bid % nTm) * BM;
  const int n0 = (bid / nTm) * BN;

  // staging: thread t covers row (t>>2); storage slot s holds global chunk
  // s ^ f(row), f(row) = (row>>1)&3  -> frag reads conflict-free (verified 0)
  const int srow = tid >> 2;
  const int schunk = (tid & 3) ^ ((srow >> 1) & 3);
  const u16* gA = A + (int64_t)(m0 + srow) * 1024 + schunk * 8;
  const u16* gB = Bm + (int64_t)(n0 + srow) * 1024 + schunk * 8;
  const int sdst = wid * 512;   // u16 offset; +j*2048; HW adds lane*16B

#define STAGE(b, t) do { const int _ko = (t) * 32; \
    _Pragma("unroll") for (int j = 0; j < LA; ++j) \
      gload_lds16(gA + (int64_t)(j * 64) * 1024 + _ko, &SA[b][j * 2048 + sdst]); \
    _Pragma("unroll") for (int j = 0; j < LB; ++j) \
      gload_lds16(gB + (int64_t)(j * 64) * 1024 + _ko, &SB[b][j * 2048 + sdst]); } while (0)

  f32x4 acc[MREP][NREP];
  #pragma unroll
  for (int i = 0; i < MREP; ++i)
    #pragma unroll
    for (int j = 0; j < NREP; ++j)
      #pragma unroll
      for (int e = 0; e < 4; ++e) acc[i][j][e] = 0.0f;

  const int rchunk = (lg ^ ((lr >> 1) & 3)) * 8;   // swizzled 16B-slot for frag reads

  STAGE(0, 0);
  STAGE(1, 1);
  waitvm<LOADS>();    // tile0 landed (tile1 may still be in flight)
  BARRIER();

  int bc = 0, bs = 2;   // compute buffer, stage-target buffer
  for (int t = 0; t < 32; ++t) {
    if (t < 30) STAGE(bs, t + 2);
    const u16* sa = SA[bc];
    const u16* sb = SB[bc];
    bf16x8 af[MREP], bfm[NREP];
    #pragma unroll
    for (int i = 0; i < MREP; ++i) af[i] = *(const bf16x8*)&sa[(wm + i * 16 + lr) * 32 + rchunk];
    #pragma unroll
    for (int i = 0; i < NREP; ++i) bfm[i] = *(const bf16x8*)&sb[(wn + i * 16 + lr) * 32 + rchunk];
    #pragma unroll
    for (int mi = 0; mi < MREP; ++mi)
      #pragma unroll
      for (int ni = 0; ni < NREP; ++ni)
        acc[mi][ni] = __builtin_amdgcn_mfma_f32_16x16x32_bf16(af[mi], bfm[ni], acc[mi][ni], 0, 0, 0);
    if (t < 30) waitvm<LOADS>();   // tile t+1 landed; just-issued t+2 stays in flight
    else        waitvm<0>();
    BARRIER();
    bc = (bc == 2) ? 0 : bc + 1;
    bs = (bs == 2) ? 0 : bs + 1;
  }

  if (MODE == 0) {
    #pragma unroll
    for (int mi = 0; mi < MREP; ++mi)
      #pragma unroll
      for (int r = 0; r < 4; ++r) {
        const int row = m0 + wm + mi * 16 + lg * 4 + r;
        float* orow = outf + (int64_t)row * 1024 + n0 + wn + lr;
        #pragma unroll
        for (int ni = 0; ni < NREP; ++ni) orow[ni * 16] = acc[mi][ni][r];
      }
  } else {
    #pragma unroll
    for (int mi = 0; mi < MREP; ++mi) {
      #pragma unroll
      for (int r = 0; r < 4; ++r) {
        const int row = m0 + wm + mi * 16 + lg * 4 + r;
        const int bb = row >> 11, ss = row & 2047;
        #pragma unroll
        for (int ni = 0; ni < NREP; ++ni) {
          const int n = n0 + wn + ni * 16 + lr;
          float v = acc[mi][ni][r];
          if (n < 2048) {                       // Q or K: RoPE (block-uniform branch)
            float partner = __shfl_xor(v, 1);
            const int ii = (n >> 1) & 31;
            const float c = cosT[ss * 32 + ii];
            const float sn = sinT[ss * 32 + ii];
            float rv = (n & 1) ? (partner * sn + v * c) : (v * c - partner * sn);
            const int h = (n >> 6) & 15, d = n & 63;
            const int idx = ((bb * 16 + h) * 2048 + ss) * 64 + d;
            // Q: fold 1/sqrt(D)=1/32 AND log2(e) so softmax runs in exp2 domain
            if (n < 1024) Qb[idx] = f2bf(rv * 0.0450842298f);
            else          Kb[idx] = f2bf(rv);
          } else {                              // V: store transposed [bh][d][s]
            const int n2 = n - 2048;
            const int h = n2 >> 6, d = n2 & 63;
            VbT[((int64_t)(bb * 16 + h) * 64 + d) * 2048 + ss] = f2bf(v);
          }
        }
      }
    }
  }
#undef STAGE
}

// ---------- 3: flash attention, KVBLK=128 as 2 sub-tiles of proven [64][64] layout ----------
// grid: 512 = 32 (b*h) * 16 qblocks; block: 4 waves, each owns 32 q-rows.
// swapped QK^T: S^T = mfma32x32x16(K, Q) -> lane owns query ql; per sub-tile
// 32 of 64 key-scores in-lane (hi split with lane^32 partner).
// P fragments built fully in-register via v_cvt_pk_bf16_f32 + v_permlane32_swap.
__global__ __launch_bounds__(256, 2)
void attn_kernel(const u16* __restrict__ Qb, const u16* __restrict__ Kb,
                 const u16* __restrict__ VbT, u16* __restrict__ attnb,
                 const int* __restrict__ lens) {
  __shared__ alignas(16) u16 Klds[2][2][64 * 64];   // [buf][sub][key][d], slot^=(key&7)
  __shared__ alignas(16) u16 Vlds[2][2][64 * 64];   // [buf][sub][d][key], slot^=(d&7)
  const int tid = threadIdx.x, lane = tid & 63, wid = tid >> 6;
  const int hi = lane >> 5, ql = lane & 31;
  const int bh = blockIdx.x >> 4;
  const int len = lens[bh >> 4];
  const int qrow = (blockIdx.x & 15) * 128 + wid * 32 + ql;

  // Q fragments (loop-invariant): B-operand, chunk c: d = c*16 + hi*8 + j
  bf16x8 qf[4];
  const u16* qptr = Qb + ((int64_t)bh * 2048 + qrow) * 64 + hi * 8;
  #pragma unroll
  for (int c = 0; c < 4; ++c) qf[c] = *(const bf16x8*)(qptr + c * 16);

  // staging: pre-swizzled global source, linear LDS dest (G21)
  const int srow = tid >> 3, schunk = (tid & 7) ^ (srow & 7);
  const u16* kg = Kb + ((int64_t)bh * 2048 + srow) * 64 + schunk * 8;    // srow = key row
  const u16* vg = VbT + ((int64_t)bh * 64 + srow) * 2048 + schunk * 8;   // srow = d row
  const int dstoff = wid * 512;                  // u16; HW adds lane*16B

  // stage one 128-key tile t into buffer b (8 gloads)
#define ASTAGE(b, t) do { const int _k0 = (t) * 128; \
    _Pragma("unroll") for (int su = 0; su < 2; ++su) { \
      gload_lds16(kg + (int64_t)(_k0 + su * 64) * 64,        &Klds[b][su][dstoff]); \
      gload_lds16(kg + (int64_t)(_k0 + su * 64 + 32) * 64,   &Klds[b][su][2048 + dstoff]); \
      gload_lds16(vg + _k0 + su * 64,                        &Vlds[b][su][dstoff]); \
      gload_lds16(vg + _k0 + su * 64 + 32 * 2048,            &Vlds[b][su][2048 + dstoff]); } } while (0)

  f32x16 oacc[2];
  #pragma unroll
  for (int r = 0; r < 16; ++r) { oacc[0][r] = 0.0f; oacc[1][r] = 0.0f; }
  float mrun = -1e30f, lrun = 0.0f;

  const int nt = (len + 127) >> 7;
  ASTAGE(0, 0);
  __syncthreads();

  for (int t = 0; t < nt; ++t) {
    const int bu = t & 1;
    if (t + 1 < nt) ASTAGE(bu ^ 1, t + 1);   // prefetch next tile into other buffer

    // QK^T: A = K rows (key = su*64 + h*32 + ql), B = Q frags
    f32x16 s[2][2];
    #pragma unroll
    for (int su = 0; su < 2; ++su)
      #pragma unroll
      for (int h = 0; h < 2; ++h)
        #pragma unroll
        for (int r = 0; r < 16; ++r) s[su][h][r] = 0.0f;
    __builtin_amdgcn_s_setprio(1);
    #pragma unroll
    for (int su = 0; su < 2; ++su)
      #pragma unroll
      for (int c = 0; c < 4; ++c) {
        const int slot = (((2 * c + hi) ^ (ql & 7)) * 8);
        bf16x8 kf0 = *(const bf16x8*)&Klds[bu][su][ql * 64 + slot];
        bf16x8 kf1 = *(const bf16x8*)&Klds[bu][su][(32 + ql) * 64 + slot];
        s[su][0] = __builtin_amdgcn_mfma_f32_32x32x16_bf16(kf0, qf[c], s[su][0], 0, 0, 0);
        s[su][1] = __builtin_amdgcn_mfma_f32_32x32x16_bf16(kf1, qf[c], s[su][1], 0, 0, 0);
      }
    __builtin_amdgcn_s_setprio(0);

    const int k0 = t * 128;
    if (k0 + 128 > len) {                    // mask padded keys (last tile only)
      #pragma unroll
      for (int su = 0; su < 2; ++su)
        #pragma unroll
        for (int r = 0; r < 16; ++r) {
          const int key = k0 + su * 64 + (r & 3) + 8 * (r >> 2) + 4 * hi;
          if (key >= len)      s[su][0][r] = -1e30f;
          if (key + 32 >= len) s[su][1][r] = -1e30f;
        }
    }

    // online softmax (exp2 domain; log2e folded into Q)
    float ma = -1e30f, mb = -1e30f, mc = -1e30f, md = -1e30f;
    #pragma unroll
    for (int su = 0; su < 2; ++su)
      #pragma unroll
      for (int h = 0; h < 2; ++h)
        #pragma unroll
        for (int r = 0; r < 16; r += 4) {
          ma = fmaxf(ma, s[su][h][r]);
          mb = fmaxf(mb, s[su][h][r + 1]);
          mc = fmaxf(mc, s[su][h][r + 2]);
          md = fmaxf(md, s[su][h][r + 3]);
        }
    float mx = fmaxf(fmaxf(ma, mb), fmaxf(mc, md));
    mx = fmaxf(mx, __shfl_xor(mx, 32));
    if (!__all(mx - mrun <= 11.0f)) {       // defer-max (T13): rescale only on real growth
      const float mnew = fmaxf(mrun, mx);
      const float sc = exp2_fast(mrun - mnew);
      #pragma unroll
      for (int r = 0; r < 16; ++r) { oacc[0][r] *= sc; oacc[1][r] *= sc; }
      lrun *= sc;
      mrun = mnew;
    }

    // p + pfrag per sub-tile (T12: cvt_pk + permlane32_swap, fully in-register)
    float ps0 = 0.0f, ps1 = 0.0f;
    bf16x8 pfrag[8];
    #pragma unroll
    for (int su = 0; su < 2; ++su) {
      float p0[16], p1[16];
      #pragma unroll
      for (int r = 0; r < 16; r += 2) {
        p0[r]     = exp2_fast(s[su][0][r] - mrun);
        p0[r + 1] = exp2_fast(s[su][0][r + 1] - mrun);
        p1[r]     = exp2_fast(s[su][1][r] - mrun);
        p1[r + 1] = exp2_fast(s[su][1][r + 1] - mrun);
        ps0 += p0[r] + p1[r];
        ps1 += p0[r + 1] + p1[r + 1];
      }
      #pragma unroll
      for (int ks = 0; ks < 4; ++ks) {
        const float* pp = (ks < 2) ? p0 : p1;
        const int o = (ks & 1) * 8;
        uint32_t a0, a1, a2, a3;
        CVTPK(a0, pp[o + 0], pp[o + 1]);
        CVTPK(a1, pp[o + 2], pp[o + 3]);
        CVTPK(a2, pp[o + 4], pp[o + 5]);
        CVTPK(a3, pp[o + 6], pp[o + 7]);
        SWAP32(a0, a2);
        SWAP32(a1, a3);
        union { uint32_t u[4]; bf16x8 v; } pw;
        pw.u[0] = a0; pw.u[1] = a1; pw.u[2] = a2; pw.u[3] = a3;
        pfrag[su * 4 + ks] = pw.v;
      }
    }
    float psum = ps0 + ps1;
    psum += __shfl_xor(psum, 32);
    lrun += psum;

    // PV: O^T += V^T * P   (A = V^T rows d = dc*32 + ql, per sub-tile)
    __builtin_amdgcn_s_setprio(1);
    #pragma unroll
    for (int dc = 0; dc < 2; ++dc) {
      const int drow = dc * 32 + ql;
      #pragma unroll
      for (int su = 0; su < 2; ++su)
        #pragma unroll
        for (int ks = 0; ks < 4; ++ks) {
          const int slot = (((2 * ks + hi) ^ (ql & 7)) * 8);
          bf16x8 vf = *(const bf16x8*)&Vlds[bu][su][drow * 64 + slot];
          oacc[dc] = __builtin_amdgcn_mfma_f32_32x32x16_bf16(vf, pfrag[su * 4 + ks], oacc[dc], 0, 0, 0);
        }
    }
    __builtin_amdgcn_s_setprio(0);
    __syncthreads();
  }
#undef ASTAGE

  // epilogue: normalize, write attn[row][h*64+d] as bf16
  const float inv = 1.0f / lrun;
  u16* outp = attnb + ((int64_t)((bh >> 4) * 2048 + qrow)) * 1024 + (bh & 15) * 64;
  #pragma unroll
  for (int dc = 0; dc < 2; ++dc)
    #pragma unroll
    for (int g = 0; g < 4; ++g) {
      ushort4 w;
      w.x = f2bf(oacc[dc][4 * g + 0] * inv);
      w.y = f2bf(oacc[dc][4 * g + 1] * inv);
      w.z = f2bf(oacc[dc][4 * g + 2] * inv);
      w.w = f2bf(oacc[dc][4 * g + 3] * inv);
      *(ushort4*)(outp + dc * 32 + 8 * g + 4 * hi) = w;
    }
}

// ---------- launch ----------
extern "C" void kernel_launch(void* const* d_in, const int* in_sizes, int n_in,
                              void* d_out, int out_size, void* d_ws, size_t ws_size,
                              hipStream_t stream) {
  const float* x    = (const float*)d_in[0];
  const float* wq   = (const float*)d_in[1];
  const float* wk   = (const float*)d_in[2];
  const float* wv   = (const float*)d_in[3];
  const float* wo   = (const float*)d_in[4];
  const float* fcos = (const float*)d_in[5];
  const float* fsin = (const float*)d_in[6];
  const int*   pmsk = (const int*)d_in[7];
  float* out = (float*)d_out;

  char* ws = (char*)d_ws;
  u16* XB    = (u16*)(ws);                          // 8 MB
  u16* WQKV  = (u16*)(ws + (size_t)8  * 1048576);   // 6 MB
  u16* WOB   = (u16*)(ws + (size_t)14 * 1048576);   // 2 MB
  u16* QB    = (u16*)(ws + (size_t)16 * 1048576);   // 8 MB
  u16* KB    = (u16*)(ws + (size_t)24 * 1048576);   // 8 MB
  u16* VBT   = (u16*)(ws + (size_t)32 * 1048576);   // 8 MB
  u16* ATTNB = (u16*)(ws + (size_t)40 * 1048576);   // 8 MB
  int* LENS  = (int*)(ws + (size_t)48 * 1048576);

  cvt_kernel<<<2048, 256, 0, stream>>>((const float4*)x, (const float4*)wq,
                                       (const float4*)wk, (const float4*)wv,
                                       (const float4*)wo, (ushort4*)XB,
                                       (ushort4*)WQKV, (ushort4*)WOB);
  len_kernel<<<2, 256, 0, stream>>>(pmsk, LENS);

  // QKV projection: M=4096 (32 m-tiles), N=3072 (24 n-tiles) -> 768 blocks
  gemm3<128, 128, 1><<<768, 256, 0, stream>>>(XB, WQKV, 32, nullptr,
                                              QB, KB, VBT, fcos, fsin);

  attn_kernel<<<512, 256, 0, stream>>>(QB, KB, VBT, ATTNB, LENS);

  // out-proj: M=4096 (32 m-tiles), N=1024 (16 n-tiles of 64) -> 512 blocks
  gemm3<128, 64, 0><<<512, 256, 0, stream>>>(ATTNB, WOB, 32, out,
                                             nullptr, nullptr, nullptr, nullptr, nullptr);
}